// Round 3
// baseline (843.024 us; speedup 1.0000x reference)
//
#include <hip/hip_runtime.h>
#include <hip/hip_bf16.h>

#define BB 4
#define CC 128
#define HH 96
#define WW 96
#define PX (HH*WW)      // 9216 pixels
#define HP 98
#define WP 98
#define PP (HP*WP)      // 9604 padded pixels
#define K2 1152         // 128*9
#define BN_EPS 1e-5f

typedef __hip_bfloat16 bf16;
__device__ __forceinline__ float b2f(bf16 v) { return __bfloat162float(v); }

// flexible input load: f==1 -> f32 source, f==0 -> bf16 source
__device__ __forceinline__ float ldin(const void* p, size_t i, int f) {
  return f ? ((const float*)p)[i] : b2f(((const bf16*)p)[i]);
}

// prm layout (floats): [0]b_in(128) [128]b_off(18) [160]b_def(128)
//                      [288]bn1(512) [800]b_std(128) [928]bn2(512) [1440]b_out(256)
#define P_BIN  0
#define P_BOFF 128
#define P_BDEF 160
#define P_BN1  288
#define P_BSTD 800
#define P_BN2  928
#define P_BOUT 1440

// ---------------------------------------------------------------------------
// Probe: detect input dtype via bn1 gamma row (exact 1.0s). f32 word of 1.0 is
// 0x3F800000; two bf16 1.0s pack to 0x3F803F80. Also convert params to f32.
// ---------------------------------------------------------------------------
__global__ __launch_bounds__(256) void probe_params(
    const void* bn1, const void* b_in, const void* b_off, const void* b_def,
    const void* b_std, const void* bn2, const void* b_out,
    int* __restrict__ flag, float* __restrict__ prm) {
  int f = (((const unsigned*)bn1)[0] == 0x3F800000u) ? 1 : 0;
  if (threadIdx.x == 0) flag[0] = f;
  int t = threadIdx.x;
  if (t < 128) prm[P_BIN + t]  = ldin(b_in, t, f);
  if (t < 18)  prm[P_BOFF + t] = ldin(b_off, t, f);
  if (t < 128) prm[P_BDEF + t] = ldin(b_def, t, f);
  for (int i = t; i < 512; i += 256) prm[P_BN1 + i] = ldin(bn1, i, f);
  if (t < 128) prm[P_BSTD + t] = ldin(b_std, t, f);
  for (int i = t; i < 512; i += 256) prm[P_BN2 + i] = ldin(bn2, i, f);
  if (t < 256) prm[P_BOUT + t] = ldin(b_out, t, f);
}

// ---------------------------------------------------------------------------
// Weight prep: transpose to [K][M] bf16 (w_off -> f32), dtype-flex source.
// ---------------------------------------------------------------------------
__global__ __launch_bounds__(256) void prep_weights(
    const void* w_in, const void* w_def, const void* w_std, const void* w_out,
    const void* w_off,
    bf16* __restrict__ w_inT, bf16* __restrict__ w_defT,
    bf16* __restrict__ w_stdT, bf16* __restrict__ w_outT,
    float* __restrict__ w_offF, const int* __restrict__ flag) {
  int f = flag[0];
  int i = blockIdx.x * 256 + threadIdx.x;      // grid covers K2*128 = 147456
  if (i < 128 * 128) { int k = i >> 7, o = i & 127;
                       w_inT[i] = __float2bfloat16(ldin(w_in, o * 128 + k, f)); }
  if (i < K2 * 128)  { int k = i >> 7, o = i & 127;
                       w_defT[i] = __float2bfloat16(ldin(w_def, (size_t)o * K2 + k, f));
                       w_stdT[i] = __float2bfloat16(ldin(w_std, (size_t)o * K2 + k, f)); }
  if (i < 256 * 256) { int k = i >> 8, o = i & 255;
                       w_outT[i] = __float2bfloat16(ldin(w_out, o * 256 + k, f)); }
  if (i < 18 * K2)   { w_offF[i] = ldin(w_off, i, f); }
}

// ---------------------------------------------------------------------------
// 1x1 conv (128->128): x (dtype-flex) image bg -> PADDED bf16 xc slot bl.
// Tiled GEMM 64(o) x 64(p), K chunks of 32, f32 accumulate.
// ---------------------------------------------------------------------------
__global__ __launch_bounds__(256) void conv1x1_in(
    const void* __restrict__ x, const bf16* __restrict__ wT,
    const float* __restrict__ prm, bf16* __restrict__ xc,
    const int* __restrict__ flag, int b0) {
  __shared__ float wt[32][64];
  __shared__ float xt[32][64];
  int f = flag[0];
  int tid = threadIdx.x;
  int p0 = blockIdx.x * 64, o0 = blockIdx.y * 64;
  int bg = b0 + blockIdx.z, bl = blockIdx.z;
  int tx = tid & 15, ty = tid >> 4;
  float acc[4][4] = {};
  for (int k0 = 0; k0 < 128; k0 += 32) {
#pragma unroll
    for (int r = 0; r < 8; ++r) {
      int idx = tid + r * 256;
      int kk = idx >> 6, l = idx & 63;
      wt[kk][l] = b2f(wT[(k0 + kk) * 128 + o0 + l]);
      xt[kk][l] = ldin(x, (size_t)(bg * 128 + k0 + kk) * PX + p0 + l, f);
    }
    __syncthreads();
#pragma unroll
    for (int kk = 0; kk < 32; ++kk) {
      float wa[4], xa[4];
      *(float4*)wa = *(const float4*)&wt[kk][ty * 4];
      *(float4*)xa = *(const float4*)&xt[kk][tx * 4];
#pragma unroll
      for (int i = 0; i < 4; ++i)
#pragma unroll
        for (int j = 0; j < 4; ++j) acc[i][j] = fmaf(wa[i], xa[j], acc[i][j]);
    }
    __syncthreads();
  }
#pragma unroll
  for (int i = 0; i < 4; ++i) {
    int o = o0 + ty * 4 + i;
    float bs = prm[P_BIN + o];
#pragma unroll
    for (int j = 0; j < 4; ++j) {
      int p = p0 + tx * 4 + j;
      int h = p / WW, w = p - h * WW;
      xc[((size_t)bl * CC + o) * PP + (h + 1) * WP + (w + 1)] =
          __float2bfloat16(acc[i][j] + bs);
    }
  }
}

// ---------------------------------------------------------------------------
// Offset conv: 3x3, 128 -> 18 channels, padded bf16 xc slot -> f32 off slot.
// ---------------------------------------------------------------------------
__global__ __launch_bounds__(256) void conv_off_k(
    const bf16* __restrict__ xc, const float* __restrict__ wf,
    const float* __restrict__ prm, float* __restrict__ off) {
  int p = blockIdx.x * 256 + threadIdx.x;
  int o = blockIdx.y, bl = blockIdx.z;
  int h = p / WW, w = p - h * WW;
  const bf16* xb = xc + (size_t)bl * CC * PP + h * WP + w;
  const float* wr = wf + o * K2;
  float acc = prm[P_BOFF + o];
  for (int c = 0; c < CC; ++c) {
    const bf16* xp = xb + (size_t)c * PP;
    const float* wc = wr + c * 9;
#pragma unroll
    for (int i = 0; i < 3; ++i)
#pragma unroll
      for (int j = 0; j < 3; ++j)
        acc = fmaf(wc[i * 3 + j], b2f(xp[i * WP + j]), acc);
  }
  off[(size_t)(bl * 18 + o) * PX + p] = acc;
}

// ---------------------------------------------------------------------------
// Deformable branch: bilinear sample bf16 xc slot, implicit GEMM K=1152,
// bias + BN1 + ReLU -> channels [0,128) of bf16 ycat slot.
// Block: 32 pixels x 128 out channels, 256 threads (4o x 4p each).
// ---------------------------------------------------------------------------
__global__ __launch_bounds__(256) void deform_conv_k(
    const bf16* __restrict__ xc, const float* __restrict__ off,
    const bf16* __restrict__ wT, const float* __restrict__ prm,
    bf16* __restrict__ ycat) {
  __shared__ int   s_ofs[288][4];
  __shared__ float s_g[288][4];
  __shared__ float wt[36][128];
  __shared__ float xt[36][32];
  int tid = threadIdx.x;
  int p0 = blockIdx.x * 32;
  int bl = blockIdx.y;
  int h0 = p0 / WW, w0 = p0 - h0 * WW;   // 96%32==0: all 32 pixels share h0

  // phase 0: bilinear metadata for 9 taps x 32 pixels (exact ref semantics)
  for (int it = tid; it < 288; it += 256) {
    int n = it >> 5, pl = it & 31;
    int p = p0 + pl;
    float ox = off[(size_t)(bl * 18 + n) * PX + p];
    float oy = off[(size_t)(bl * 18 + 9 + n) * PX + p];
    float px = ox + (float)(n / 3 - 1) + (float)(h0 + 1);
    float py = oy + (float)(n % 3 - 1) + (float)(w0 + pl + 1);
    float qx = floorf(px), qy = floorf(py);
    float ltx = fminf(fmaxf(qx, 0.f), (float)(HP - 1));
    float lty = fminf(fmaxf(qy, 0.f), (float)(WP - 1));
    float rbx = fminf(fmaxf(qx + 1.f, 0.f), (float)(HP - 1));
    float rby = fminf(fmaxf(qy + 1.f, 0.f), (float)(WP - 1));
    float pxc = fminf(fmaxf(px, 0.f), (float)(HP - 1));
    float pyc = fminf(fmaxf(py, 0.f), (float)(WP - 1));
    float ax = 1.f + (ltx - pxc), bx = 1.f - (rbx - pxc);
    float ay = 1.f + (lty - pyc), by = 1.f - (rby - pyc);
    int iltx = (int)ltx, ilty = (int)lty, irbx = (int)rbx, irby = (int)rby;
    s_ofs[it][0] = iltx * WP + ilty;   // lt
    s_ofs[it][1] = irbx * WP + irby;   // rb
    s_ofs[it][2] = iltx * WP + irby;   // lb  (lt_x, rb_y)
    s_ofs[it][3] = irbx * WP + ilty;   // rt  (rb_x, lt_y)
    s_g[it][0] = ax * ay; s_g[it][1] = bx * by;
    s_g[it][2] = ax * by; s_g[it][3] = bx * ay;
  }
  __syncthreads();

  int tx = tid & 7, ty = tid >> 3;
  float acc[4][4] = {};
  const bf16* xb = xc + (size_t)bl * CC * PP;
  for (int c0 = 0; c0 < CC; c0 += 4) {    // K chunk = 36
#pragma unroll
    for (int r = 0; r < 18; ++r) {        // stage 36x128 weights
      int idx = tid + r * 256;
      int kk = idx >> 7, ol = idx & 127;
      wt[kk][ol] = b2f(wT[(size_t)(c0 * 9 + kk) * 128 + ol]);
    }
    for (int it = tid; it < 1152; it += 256) {   // stage sampled tile 36x32
      int kk = it >> 5, pl = it & 31;
      int c = c0 + kk / 9, n = kk % 9;
      int m = n * 32 + pl;
      const bf16* xpc = xb + (size_t)c * PP;
      float v = s_g[m][0] * b2f(xpc[s_ofs[m][0]]) +
                s_g[m][1] * b2f(xpc[s_ofs[m][1]]) +
                s_g[m][2] * b2f(xpc[s_ofs[m][2]]) +
                s_g[m][3] * b2f(xpc[s_ofs[m][3]]);
      xt[kk][pl] = v;
    }
    __syncthreads();
#pragma unroll
    for (int kk = 0; kk < 36; ++kk) {
      float wa[4], xa[4];
      *(float4*)wa = *(const float4*)&wt[kk][ty * 4];
      *(float4*)xa = *(const float4*)&xt[kk][tx * 4];
#pragma unroll
      for (int i = 0; i < 4; ++i)
#pragma unroll
        for (int j = 0; j < 4; ++j) acc[i][j] = fmaf(wa[i], xa[j], acc[i][j]);
    }
    __syncthreads();
  }
#pragma unroll
  for (int i = 0; i < 4; ++i) {
    int o = ty * 4 + i;
    float bd = prm[P_BDEF + o];
    float g  = prm[P_BN1 + o],       be = prm[P_BN1 + 128 + o];
    float mn = prm[P_BN1 + 256 + o], vr = prm[P_BN1 + 384 + o];
    float inv = g / sqrtf(vr + BN_EPS);
    float add = be - mn * inv;
#pragma unroll
    for (int j = 0; j < 4; ++j) {
      int p = p0 + tx * 4 + j;
      float v = fmaxf((acc[i][j] + bd) * inv + add, 0.f);
      ycat[((size_t)bl * 256 + o) * PX + p] = __float2bfloat16(v);
    }
  }
}

// ---------------------------------------------------------------------------
// Standard 3x3 branch: implicit GEMM K=1152 from padded bf16 xc slot,
// bias + BN2 + ReLU + residual(xc). Channels [128,256) of ycat slot.
// ---------------------------------------------------------------------------
__global__ __launch_bounds__(256) void std_conv_k(
    const bf16* __restrict__ xc, const bf16* __restrict__ wT,
    const float* __restrict__ prm, bf16* __restrict__ ycat) {
  __shared__ float wt[36][128];
  __shared__ float xt[36][32];
  int tid = threadIdx.x;
  int p0 = blockIdx.x * 32;
  int bl = blockIdx.y;
  int h0 = p0 / WW, w0 = p0 - h0 * WW;
  int tx = tid & 7, ty = tid >> 3;
  float acc[4][4] = {};
  const bf16* xb = xc + (size_t)bl * CC * PP;
  for (int c0 = 0; c0 < CC; c0 += 4) {
#pragma unroll
    for (int r = 0; r < 18; ++r) {
      int idx = tid + r * 256;
      int kk = idx >> 7, ol = idx & 127;
      wt[kk][ol] = b2f(wT[(size_t)(c0 * 9 + kk) * 128 + ol]);
    }
    for (int it = tid; it < 1152; it += 256) {
      int kk = it >> 5, pl = it & 31;
      int c = c0 + kk / 9, n = kk % 9;
      int i = n / 3, j = n % 3;
      xt[kk][pl] = b2f(xb[((size_t)c * HP + h0 + i) * WP + w0 + j + pl]);
    }
    __syncthreads();
#pragma unroll
    for (int kk = 0; kk < 36; ++kk) {
      float wa[4], xa[4];
      *(float4*)wa = *(const float4*)&wt[kk][ty * 4];
      *(float4*)xa = *(const float4*)&xt[kk][tx * 4];
#pragma unroll
      for (int i = 0; i < 4; ++i)
#pragma unroll
        for (int j = 0; j < 4; ++j) acc[i][j] = fmaf(wa[i], xa[j], acc[i][j]);
    }
    __syncthreads();
  }
#pragma unroll
  for (int i = 0; i < 4; ++i) {
    int o = ty * 4 + i;
    float bs = prm[P_BSTD + o];
    float g  = prm[P_BN2 + o],       be = prm[P_BN2 + 128 + o];
    float mn = prm[P_BN2 + 256 + o], vr = prm[P_BN2 + 384 + o];
    float inv = g / sqrtf(vr + BN_EPS);
    float add = be - mn * inv;
#pragma unroll
    for (int j = 0; j < 4; ++j) {
      int p = p0 + tx * 4 + j;
      int w = w0 + tx * 4 + j;
      float res = b2f(xb[((size_t)o * HP + h0 + 1) * WP + w + 1]);
      float v = fmaxf((acc[i][j] + bs) * inv + add, 0.f) + res;
      ycat[((size_t)bl * 256 + 128 + o) * PX + p] = __float2bfloat16(v);
    }
  }
}

// ---------------------------------------------------------------------------
// Final 1x1 conv: 256 -> 256 over bf16 ycat slot -> dtype-flex output bg.
// ---------------------------------------------------------------------------
__global__ __launch_bounds__(256) void conv1x1_out(
    const bf16* __restrict__ ycat, const bf16* __restrict__ wT,
    const float* __restrict__ prm, void* __restrict__ out,
    const int* __restrict__ flag, int b0) {
  __shared__ float wt[32][64];
  __shared__ float xt[32][64];
  int f = flag[0];
  int tid = threadIdx.x;
  int p0 = blockIdx.x * 64, o0 = blockIdx.y * 64;
  int bg = b0 + blockIdx.z, bl = blockIdx.z;
  int tx = tid & 15, ty = tid >> 4;
  float acc[4][4] = {};
  const bf16* xbase = ycat + (size_t)bl * 256 * PX;
  for (int k0 = 0; k0 < 256; k0 += 32) {
#pragma unroll
    for (int r = 0; r < 8; ++r) {
      int idx = tid + r * 256;
      int kk = idx >> 6, l = idx & 63;
      wt[kk][l] = b2f(wT[(size_t)(k0 + kk) * 256 + o0 + l]);
      xt[kk][l] = b2f(xbase[(size_t)(k0 + kk) * PX + p0 + l]);
    }
    __syncthreads();
#pragma unroll
    for (int kk = 0; kk < 32; ++kk) {
      float wa[4], xa[4];
      *(float4*)wa = *(const float4*)&wt[kk][ty * 4];
      *(float4*)xa = *(const float4*)&xt[kk][tx * 4];
#pragma unroll
      for (int i = 0; i < 4; ++i)
#pragma unroll
        for (int j = 0; j < 4; ++j) acc[i][j] = fmaf(wa[i], xa[j], acc[i][j]);
    }
    __syncthreads();
  }
#pragma unroll
  for (int i = 0; i < 4; ++i) {
    int o = o0 + ty * 4 + i;
    float bs = prm[P_BOUT + o];
#pragma unroll
    for (int j = 0; j < 4; ++j) {
      int p = p0 + tx * 4 + j;
      size_t idx = ((size_t)bg * 256 + o) * PX + p;
      float v = acc[i][j] + bs;
      if (f) ((float*)out)[idx] = v;
      else   ((bf16*)out)[idx] = __float2bfloat16(v);
    }
  }
}

// ---------------------------------------------------------------------------
extern "C" void kernel_launch(void* const* d_in, const int* in_sizes, int n_in,
                              void* d_out, int out_size, void* d_ws, size_t ws_size,
                              hipStream_t stream) {
  const void* x     = d_in[0];
  const void* w_in  = d_in[1];
  const void* b_in  = d_in[2];
  const void* w_off = d_in[3];
  const void* b_off = d_in[4];
  const void* w_def = d_in[5];
  const void* b_def = d_in[6];
  const void* bn1   = d_in[7];
  const void* w_std = d_in[8];
  const void* b_std = d_in[9];
  const void* bn2   = d_in[10];
  const void* w_out = d_in[11];
  const void* b_out = d_in[12];

  // ---- fixed workspace area (847,872 B) ----
  char* wsb = (char*)d_ws;
  int*   flag   = (int*)wsb;                     // @0
  float* prm    = (float*)(wsb + 1024);          // 1696 floats
  float* w_offF = (float*)(wsb + 8192);          // 20736 f32 = 82,944 B
  bf16*  w_inT  = (bf16*)(wsb + 91136);          // 16384 bf16
  bf16*  w_defT = (bf16*)(wsb + 123904);         // 147456 bf16
  bf16*  w_stdT = (bf16*)(wsb + 418816);         // 147456 bf16
  bf16*  w_outT = (bf16*)(wsb + 713728);         // 65536 bf16
  const size_t FIXED = 847872;

  // ---- per-image scratch, chunked to fit ws_size ----
  const size_t XCB  = (size_t)CC * PP * sizeof(bf16);   // 2,459,648
  const size_t OFFB = (size_t)18 * PX * sizeof(float);  //   663,552
  const size_t YCB  = (size_t)256 * PX * sizeof(bf16);  // 4,718,592
  const size_t PERB = XCB + OFFB + YCB;                 // 7,841,792
  int nb = 1;
  if (ws_size > FIXED) {
    size_t fit = (ws_size - FIXED) / PERB;
    nb = (int)(fit < 1 ? 1 : (fit > BB ? BB : fit));
  }
  bf16*  xcA  = (bf16*)(wsb + FIXED);
  float* offA = (float*)(wsb + FIXED + (size_t)nb * XCB);
  bf16*  ycA  = (bf16*)(wsb + FIXED + (size_t)nb * (XCB + OFFB));

  probe_params<<<1, 256, 0, stream>>>(bn1, b_in, b_off, b_def, b_std, bn2, b_out,
                                      flag, prm);
  // zero padded xc area once: borders stay zero across chunk reuse
  hipMemsetAsync(xcA, 0, (size_t)nb * XCB, stream);

  prep_weights<<<(K2 * 128 + 255) / 256, 256, 0, stream>>>(
      w_in, w_def, w_std, w_out, w_off, w_inT, w_defT, w_stdT, w_outT, w_offF, flag);

  for (int b0 = 0; b0 < BB; b0 += nb) {
    int nz = (BB - b0) < nb ? (BB - b0) : nb;
    conv1x1_in<<<dim3(PX / 64, 2, nz), 256, 0, stream>>>(
        x, w_inT, prm, xcA, flag, b0);
    conv_off_k<<<dim3(PX / 256, 18, nz), 256, 0, stream>>>(
        xcA, w_offF, prm, offA);
    deform_conv_k<<<dim3(PX / 32, nz), 256, 0, stream>>>(
        xcA, offA, w_defT, prm, ycA);
    std_conv_k<<<dim3(PX / 32, nz), 256, 0, stream>>>(
        xcA, w_stdT, prm, ycA);
    conv1x1_out<<<dim3(PX / 64, 4, nz), 256, 0, stream>>>(
        ycA, w_outT, prm, d_out, flag, b0);
  }
}

// Round 4
// 510.869 us; speedup vs baseline: 1.6502x; 1.6502x over previous
//
#include <hip/hip_runtime.h>
#include <hip/hip_bf16.h>

#define BB 4
#define CC 128
#define HH 96
#define WW 96
#define PX (HH*WW)      // 9216 pixels
#define HP 98
#define WP 98
#define PP (HP*WP)      // 9604 padded pixels
#define K2 1152         // 128*9
#define BN_EPS 1e-5f

typedef __hip_bfloat16 bf16;
typedef __attribute__((ext_vector_type(8))) short bf16x8;   // MFMA A/B frag
typedef __attribute__((ext_vector_type(4))) float f32x4;    // MFMA C/D frag
__device__ __forceinline__ float b2f(bf16 v) { return __bfloat162float(v); }

#define MFMA(a, b, c) __builtin_amdgcn_mfma_f32_16x16x32_bf16((a), (b), (c), 0, 0, 0)

// flexible input load: f==1 -> f32 source, f==0 -> bf16 source
__device__ __forceinline__ float ldin(const void* p, size_t i, int f) {
  return f ? ((const float*)p)[i] : b2f(((const bf16*)p)[i]);
}

// prm layout (floats): [0]b_in(128) [128]b_off(18) [160]b_def(128)
//                      [288]bn1(512) [800]b_std(128) [928]bn2(512) [1440]b_out(256)
#define P_BIN  0
#define P_BOFF 128
#define P_BDEF 160
#define P_BN1  288
#define P_BSTD 800
#define P_BN2  928
#define P_BOUT 1440

// ---------------------------------------------------------------------------
// Probe: detect input dtype via bn1 gamma row (exact 1.0s). f32 word of 1.0 is
// 0x3F800000; two bf16 1.0s pack to 0x3F803F80. Also convert params to f32.
// ---------------------------------------------------------------------------
__global__ __launch_bounds__(256) void probe_params(
    const void* bn1, const void* b_in, const void* b_off, const void* b_def,
    const void* b_std, const void* bn2, const void* b_out,
    int* __restrict__ flag, float* __restrict__ prm) {
  int f = (((const unsigned*)bn1)[0] == 0x3F800000u) ? 1 : 0;
  if (threadIdx.x == 0) flag[0] = f;
  int t = threadIdx.x;
  if (t < 128) prm[P_BIN + t]  = ldin(b_in, t, f);
  if (t < 18)  prm[P_BOFF + t] = ldin(b_off, t, f);
  if (t < 128) prm[P_BDEF + t] = ldin(b_def, t, f);
  for (int i = t; i < 512; i += 256) prm[P_BN1 + i] = ldin(bn1, i, f);
  if (t < 128) prm[P_BSTD + t] = ldin(b_std, t, f);
  for (int i = t; i < 512; i += 256) prm[P_BN2 + i] = ldin(bn2, i, f);
  if (t < 256) prm[P_BOUT + t] = ldin(b_out, t, f);
}

// ---------------------------------------------------------------------------
// Weight prep (bf16 [o][k] layouts for direct A-fragment global loads).
// w_def/w_std are K-REORDERED: k' = n*128 + c  (n = 3x3 tap, c = in-channel)
// so K-chunks of 32 stay within one tap. w_off stays f32 natural order.
// ---------------------------------------------------------------------------
__global__ __launch_bounds__(256) void prep_weights(
    const void* w_in, const void* w_def, const void* w_std, const void* w_out,
    const void* w_off,
    bf16* __restrict__ w_inB, bf16* __restrict__ w_defB,
    bf16* __restrict__ w_stdB, bf16* __restrict__ w_outB,
    float* __restrict__ w_offF, const int* __restrict__ flag) {
  int f = flag[0];
  int i = blockIdx.x * 256 + threadIdx.x;      // grid covers K2*128 = 147456
  if (i < K2 * 128) {
    int o = i / K2, kk = i - o * K2;
    int c = kk / 9, n = kk - c * 9;
    int dst = o * K2 + n * 128 + c;
    w_defB[dst] = __float2bfloat16(ldin(w_def, i, f));
    w_stdB[dst] = __float2bfloat16(ldin(w_std, i, f));
  }
  if (i < 128 * 128) w_inB[i]  = __float2bfloat16(ldin(w_in, i, f));
  if (i < 256 * 256) w_outB[i] = __float2bfloat16(ldin(w_out, i, f));
  if (i < 18 * K2)   w_offF[i] = ldin(w_off, i, f);
}

// ---------------------------------------------------------------------------
// 1x1 conv in (128->128), MFMA. Tile 32 px x 128 o; wave w: o in [32w,32w+32).
// K=128 in 4 chunks of 32. A from global w_inB, B built from x (dtype-flex).
// Writes PADDED bf16 xc. No LDS, no barriers.
// ---------------------------------------------------------------------------
__global__ __launch_bounds__(256) void conv1x1_in(
    const void* __restrict__ x, const bf16* __restrict__ wB,
    const float* __restrict__ prm, bf16* __restrict__ xc,
    const int* __restrict__ flag, int b0) {
  int f = flag[0];
  int tid = threadIdx.x;
  int p0 = blockIdx.x * 32;
  int bg = b0 + blockIdx.y, bl = blockIdx.y;
  int lane = tid & 63, wv = tid >> 6;
  int quad = lane >> 4, l16 = lane & 15;
  const float* xf = (const float*)x;
  const bf16*  xh = (const bf16*)x;
  f32x4 acc[2][2] = {};
  for (int k0 = 0; k0 < 128; k0 += 32) {
    const bf16* wp = wB + (size_t)(wv * 32 + l16) * 128 + k0 + quad * 8;
    bf16x8 a0 = *(const bf16x8*)wp;
    bf16x8 a1 = *(const bf16x8*)(wp + 16 * 128);
    bf16x8 bfr[2];
#pragma unroll
    for (int p = 0; p < 2; ++p) {
      union { bf16x8 v; bf16 h[8]; } u;
      size_t base = (size_t)(bg * 128 + k0 + quad * 8) * PX + p0 + p * 16 + l16;
#pragma unroll
      for (int j = 0; j < 8; ++j)
        u.h[j] = f ? __float2bfloat16(xf[base + (size_t)j * PX]) : xh[base + (size_t)j * PX];
      bfr[p] = u.v;
    }
#pragma unroll
    for (int p = 0; p < 2; ++p) {
      acc[0][p] = MFMA(a0, bfr[p], acc[0][p]);
      acc[1][p] = MFMA(a1, bfr[p], acc[1][p]);
    }
  }
#pragma unroll
  for (int i = 0; i < 2; ++i)
#pragma unroll
    for (int r = 0; r < 4; ++r) {
      int o = wv * 32 + i * 16 + quad * 4 + r;
      float bs = prm[P_BIN + o];
#pragma unroll
      for (int p = 0; p < 2; ++p) {
        int px = p0 + p * 16 + l16;
        int h = px / WW, w = px - h * WW;
        xc[((size_t)bl * CC + o) * PP + (size_t)(h + 1) * WP + (w + 1)] =
            __float2bfloat16(acc[i][p][r] + bs);
      }
    }
}

// ---------------------------------------------------------------------------
// Offset conv: 3x3, 128 -> 18 channels (unchanged from R3 — keeps offsets
// bit-comparable; small kernel).
// ---------------------------------------------------------------------------
__global__ __launch_bounds__(256) void conv_off_k(
    const bf16* __restrict__ xc, const float* __restrict__ wf,
    const float* __restrict__ prm, float* __restrict__ off) {
  int p = blockIdx.x * 256 + threadIdx.x;
  int o = blockIdx.y, bl = blockIdx.z;
  int h = p / WW, w = p - h * WW;
  const bf16* xb = xc + (size_t)bl * CC * PP + h * WP + w;
  const float* wr = wf + o * K2;
  float acc = prm[P_BOFF + o];
  for (int c = 0; c < CC; ++c) {
    const bf16* xp = xb + (size_t)c * PP;
    const float* wc = wr + c * 9;
#pragma unroll
    for (int i = 0; i < 3; ++i)
#pragma unroll
      for (int j = 0; j < 3; ++j)
        acc = fmaf(wc[i * 3 + j], b2f(xp[i * WP + j]), acc);
  }
  off[(size_t)(bl * 18 + o) * PX + p] = acc;
}

// ---------------------------------------------------------------------------
// Deformable branch, MFMA. Tile 32 px x 128 o; wave w: o in [32w,32w+32).
// K reordered k' = n*128+c, 36 chunks of 32 (tap n fixed per chunk).
// Gather stages bf16 tile xt[px][k] in LDS; A-frags direct from global.
// bias + BN1 + ReLU -> channels [0,128) of ycat.
// ---------------------------------------------------------------------------
__global__ __launch_bounds__(256) void deform_conv_k(
    const bf16* __restrict__ xc, const float* __restrict__ off,
    const bf16* __restrict__ wB, const float* __restrict__ prm,
    bf16* __restrict__ ycat) {
  __shared__ int   s_ofs[288][4];
  __shared__ float s_g[288][4];
  __shared__ bf16  xt[32][40];       // +8 pad: b128 frag reads conflict-free
  int tid = threadIdx.x;
  int p0 = blockIdx.x * 32;
  int bl = blockIdx.y;
  int h0 = p0 / WW, w0 = p0 - h0 * WW;   // 96%32==0: all 32 pixels share h0

  // phase 0: bilinear metadata for 9 taps x 32 pixels (exact ref semantics)
  for (int it = tid; it < 288; it += 256) {
    int n = it >> 5, pl = it & 31;
    int p = p0 + pl;
    float ox = off[(size_t)(bl * 18 + n) * PX + p];
    float oy = off[(size_t)(bl * 18 + 9 + n) * PX + p];
    float px = ox + (float)(n / 3 - 1) + (float)(h0 + 1);
    float py = oy + (float)(n % 3 - 1) + (float)(w0 + pl + 1);
    float qx = floorf(px), qy = floorf(py);
    float ltx = fminf(fmaxf(qx, 0.f), (float)(HP - 1));
    float lty = fminf(fmaxf(qy, 0.f), (float)(WP - 1));
    float rbx = fminf(fmaxf(qx + 1.f, 0.f), (float)(HP - 1));
    float rby = fminf(fmaxf(qy + 1.f, 0.f), (float)(WP - 1));
    float pxc = fminf(fmaxf(px, 0.f), (float)(HP - 1));
    float pyc = fminf(fmaxf(py, 0.f), (float)(WP - 1));
    float ax = 1.f + (ltx - pxc), bx = 1.f - (rbx - pxc);
    float ay = 1.f + (lty - pyc), by = 1.f - (rby - pyc);
    int iltx = (int)ltx, ilty = (int)lty, irbx = (int)rbx, irby = (int)rby;
    s_ofs[it][0] = iltx * WP + ilty;   // lt
    s_ofs[it][1] = irbx * WP + irby;   // rb
    s_ofs[it][2] = iltx * WP + irby;   // lb
    s_ofs[it][3] = irbx * WP + ilty;   // rt
    s_g[it][0] = ax * ay; s_g[it][1] = bx * by;
    s_g[it][2] = ax * by; s_g[it][3] = bx * ay;
  }
  __syncthreads();

  int lane = tid & 63, wv = tid >> 6;
  int quad = lane >> 4, l16 = lane & 15;
  int gpx = tid & 31, cg = (tid >> 5) << 2;    // gather: px + 4-channel group
  const bf16* xb = xc + (size_t)bl * CC * PP;
  f32x4 acc[2][2] = {};
  int4 o4; float4 g4;
  for (int ch = 0; ch < 36; ++ch) {
    int n = ch >> 2, c0 = (ch & 3) << 5;       // tap n, channel base c0
    // A frags direct from global (L2-resident, 16 full lines per frag)
    const bf16* wp = wB + (size_t)(wv * 32 + l16) * K2 + n * 128 + c0 + quad * 8;
    bf16x8 a0 = *(const bf16x8*)wp;
    bf16x8 a1 = *(const bf16x8*)(wp + 16 * K2);
    // bilinear metadata fixed per tap
    if ((ch & 3) == 0) {
      int m = n * 32 + gpx;
      o4 = *(const int4*)s_ofs[m];
      g4 = *(const float4*)s_g[m];
    }
    // gather 4 channels for my pixel
    const bf16* xpc = xb + (size_t)(c0 + cg) * PP;
    union { short4 s; bf16 h[4]; } u;
#pragma unroll
    for (int q = 0; q < 4; ++q) {
      float v = g4.x * b2f(xpc[o4.x]) + g4.y * b2f(xpc[o4.y]) +
                g4.z * b2f(xpc[o4.z]) + g4.w * b2f(xpc[o4.w]);
      u.h[q] = __float2bfloat16(v);
      xpc += PP;
    }
    *(short4*)&xt[gpx][cg] = u.s;
    __syncthreads();
    bf16x8 bf0 = *(const bf16x8*)&xt[l16][quad * 8];
    bf16x8 bf1 = *(const bf16x8*)&xt[16 + l16][quad * 8];
    acc[0][0] = MFMA(a0, bf0, acc[0][0]);
    acc[0][1] = MFMA(a0, bf1, acc[0][1]);
    acc[1][0] = MFMA(a1, bf0, acc[1][0]);
    acc[1][1] = MFMA(a1, bf1, acc[1][1]);
    __syncthreads();
  }
#pragma unroll
  for (int i = 0; i < 2; ++i)
#pragma unroll
    for (int r = 0; r < 4; ++r) {
      int o = wv * 32 + i * 16 + quad * 4 + r;
      float bd = prm[P_BDEF + o];
      float g  = prm[P_BN1 + o],       be = prm[P_BN1 + 128 + o];
      float mn = prm[P_BN1 + 256 + o], vr = prm[P_BN1 + 384 + o];
      float inv = g / sqrtf(vr + BN_EPS);
      float add = be - mn * inv;
#pragma unroll
      for (int p = 0; p < 2; ++p) {
        int px = p0 + p * 16 + l16;
        float v = fmaxf((acc[i][p][r] + bd) * inv + add, 0.f);
        ycat[((size_t)bl * 256 + o) * PX + px] = __float2bfloat16(v);
      }
    }
}

// ---------------------------------------------------------------------------
// Standard 3x3 branch, MFMA. Same skeleton as deform; im2col staging is a
// contiguous copy. bias + BN2 + ReLU + residual -> channels [128,256) of ycat.
// ---------------------------------------------------------------------------
__global__ __launch_bounds__(256) void std_conv_k(
    const bf16* __restrict__ xc, const bf16* __restrict__ wB,
    const float* __restrict__ prm, bf16* __restrict__ ycat) {
  __shared__ bf16 xt[32][40];
  int tid = threadIdx.x;
  int p0 = blockIdx.x * 32;
  int bl = blockIdx.y;
  int h0 = p0 / WW, w0 = p0 - h0 * WW;
  int lane = tid & 63, wv = tid >> 6;
  int quad = lane >> 4, l16 = lane & 15;
  int gpx = tid & 31, cg = (tid >> 5) << 2;
  const bf16* xb = xc + (size_t)bl * CC * PP;
  f32x4 acc[2][2] = {};
  for (int ch = 0; ch < 36; ++ch) {
    int n = ch >> 2, c0 = (ch & 3) << 5;
    int ti = n / 3, tj = n - ti * 3;
    const bf16* wp = wB + (size_t)(wv * 32 + l16) * K2 + n * 128 + c0 + quad * 8;
    bf16x8 a0 = *(const bf16x8*)wp;
    bf16x8 a1 = *(const bf16x8*)(wp + 16 * K2);
    const bf16* base = xb + (size_t)(c0 + cg) * PP + (size_t)(h0 + ti) * WP + w0 + tj + gpx;
    union { short4 s; bf16 h[4]; } u;
#pragma unroll
    for (int q = 0; q < 4; ++q) u.h[q] = base[(size_t)q * PP];
    *(short4*)&xt[gpx][cg] = u.s;
    __syncthreads();
    bf16x8 bf0 = *(const bf16x8*)&xt[l16][quad * 8];
    bf16x8 bf1 = *(const bf16x8*)&xt[16 + l16][quad * 8];
    acc[0][0] = MFMA(a0, bf0, acc[0][0]);
    acc[0][1] = MFMA(a0, bf1, acc[0][1]);
    acc[1][0] = MFMA(a1, bf0, acc[1][0]);
    acc[1][1] = MFMA(a1, bf1, acc[1][1]);
    __syncthreads();
  }
#pragma unroll
  for (int i = 0; i < 2; ++i)
#pragma unroll
    for (int r = 0; r < 4; ++r) {
      int o = wv * 32 + i * 16 + quad * 4 + r;
      float bs = prm[P_BSTD + o];
      float g  = prm[P_BN2 + o],       be = prm[P_BN2 + 128 + o];
      float mn = prm[P_BN2 + 256 + o], vr = prm[P_BN2 + 384 + o];
      float inv = g / sqrtf(vr + BN_EPS);
      float add = be - mn * inv;
#pragma unroll
      for (int p = 0; p < 2; ++p) {
        int pxl = p * 16 + l16;
        int px = p0 + pxl;
        float res = b2f(xb[(size_t)o * PP + (size_t)(h0 + 1) * WP + w0 + pxl + 1]);
        float v = fmaxf((acc[i][p][r] + bs) * inv + add, 0.f) + res;
        ycat[((size_t)bl * 256 + 128 + o) * PX + px] = __float2bfloat16(v);
      }
    }
}

// ---------------------------------------------------------------------------
// Final 1x1 conv (256->256), MFMA. Tile 32 px x 256 o; wave w: o in [64w,64w+64).
// K=256 in 8 chunks. A from global w_outB, B from global ycat. No LDS.
// ---------------------------------------------------------------------------
__global__ __launch_bounds__(256) void conv1x1_out(
    const bf16* __restrict__ ycat, const bf16* __restrict__ wB,
    const float* __restrict__ prm, void* __restrict__ out,
    const int* __restrict__ flag, int b0) {
  int f = flag[0];
  int tid = threadIdx.x;
  int p0 = blockIdx.x * 32;
  int bg = b0 + blockIdx.y, bl = blockIdx.y;
  int lane = tid & 63, wv = tid >> 6;
  int quad = lane >> 4, l16 = lane & 15;
  const bf16* yb = ycat + (size_t)bl * 256 * PX;
  f32x4 acc[4][2] = {};
  for (int k0 = 0; k0 < 256; k0 += 32) {
    bf16x8 a[4];
#pragma unroll
    for (int s = 0; s < 4; ++s)
      a[s] = *(const bf16x8*)(wB + (size_t)(wv * 64 + s * 16 + l16) * 256 + k0 + quad * 8);
    bf16x8 bfr[2];
#pragma unroll
    for (int p = 0; p < 2; ++p) {
      union { bf16x8 v; bf16 h[8]; } u;
      const bf16* yp = yb + (size_t)(k0 + quad * 8) * PX + p0 + p * 16 + l16;
#pragma unroll
      for (int j = 0; j < 8; ++j) u.h[j] = yp[(size_t)j * PX];
      bfr[p] = u.v;
    }
#pragma unroll
    for (int s = 0; s < 4; ++s)
#pragma unroll
      for (int p = 0; p < 2; ++p)
        acc[s][p] = MFMA(a[s], bfr[p], acc[s][p]);
  }
#pragma unroll
  for (int s = 0; s < 4; ++s)
#pragma unroll
    for (int r = 0; r < 4; ++r) {
      int o = wv * 64 + s * 16 + quad * 4 + r;
      float bs = prm[P_BOUT + o];
#pragma unroll
      for (int p = 0; p < 2; ++p) {
        int px = p0 + p * 16 + l16;
        size_t idx = ((size_t)bg * 256 + o) * PX + px;
        float v = acc[s][p][r] + bs;
        if (f) ((float*)out)[idx] = v;
        else   ((bf16*)out)[idx] = __float2bfloat16(v);
      }
    }
}

// ---------------------------------------------------------------------------
extern "C" void kernel_launch(void* const* d_in, const int* in_sizes, int n_in,
                              void* d_out, int out_size, void* d_ws, size_t ws_size,
                              hipStream_t stream) {
  const void* x     = d_in[0];
  const void* w_in  = d_in[1];
  const void* b_in  = d_in[2];
  const void* w_off = d_in[3];
  const void* b_off = d_in[4];
  const void* w_def = d_in[5];
  const void* b_def = d_in[6];
  const void* bn1   = d_in[7];
  const void* w_std = d_in[8];
  const void* b_std = d_in[9];
  const void* bn2   = d_in[10];
  const void* w_out = d_in[11];
  const void* b_out = d_in[12];

  // ---- fixed workspace area ----
  char* wsb = (char*)d_ws;
  int*   flag   = (int*)wsb;                     // @0
  float* prm    = (float*)(wsb + 1024);          // 1696 floats
  float* w_offF = (float*)(wsb + 8192);          // 20736 f32 = 82,944 B
  bf16*  w_inB  = (bf16*)(wsb + 91136);          // 16384 bf16
  bf16*  w_defB = (bf16*)(wsb + 123904);         // 147456 bf16 (reordered)
  bf16*  w_stdB = (bf16*)(wsb + 418816);         // 147456 bf16 (reordered)
  bf16*  w_outB = (bf16*)(wsb + 713728);         // 65536 bf16 -> end 844,800
  const size_t FIXED = 847872;

  // ---- per-image scratch, chunked to fit ws_size ----
  const size_t XCB  = (size_t)CC * PP * sizeof(bf16);   // 2,459,648
  const size_t OFFB = (size_t)18 * PX * sizeof(float);  //   663,552
  const size_t YCB  = (size_t)256 * PX * sizeof(bf16);  // 4,718,592
  const size_t PERB = XCB + OFFB + YCB;                 // 7,841,792
  int nb = 1;
  if (ws_size > FIXED) {
    size_t fit = (ws_size - FIXED) / PERB;
    nb = (int)(fit < 1 ? 1 : (fit > BB ? BB : fit));
  }
  bf16*  xcA  = (bf16*)(wsb + FIXED);
  float* offA = (float*)(wsb + FIXED + (size_t)nb * XCB);
  bf16*  ycA  = (bf16*)(wsb + FIXED + (size_t)nb * (XCB + OFFB));

  probe_params<<<1, 256, 0, stream>>>(bn1, b_in, b_off, b_def, b_std, bn2, b_out,
                                      flag, prm);
  // zero padded xc area once: borders stay zero across chunk reuse
  hipMemsetAsync(xcA, 0, (size_t)nb * XCB, stream);

  prep_weights<<<(K2 * 128 + 255) / 256, 256, 0, stream>>>(
      w_in, w_def, w_std, w_out, w_off, w_inB, w_defB, w_stdB, w_outB, w_offF, flag);

  for (int b0 = 0; b0 < BB; b0 += nb) {
    int nz = (BB - b0) < nb ? (BB - b0) : nb;
    conv1x1_in<<<dim3(PX / 32, nz), 256, 0, stream>>>(
        x, w_inB, prm, xcA, flag, b0);
    conv_off_k<<<dim3(PX / 256, 18, nz), 256, 0, stream>>>(
        xcA, w_offF, prm, offA);
    deform_conv_k<<<dim3(PX / 32, nz), 256, 0, stream>>>(
        xcA, offA, w_defB, prm, ycA);
    std_conv_k<<<dim3(PX / 32, nz), 256, 0, stream>>>(
        xcA, w_stdB, prm, ycA);
    conv1x1_out<<<dim3(PX / 32, nz), 256, 0, stream>>>(
        ycA, w_outB, prm, d_out, flag, b0);
  }
}